// Round 9
// baseline (226.065 us; speedup 1.0000x reference)
//
#include <hip/hip_runtime.h>
#include <cmath>

#define NK       10000
#define GROUP    2000
#define SEQ_L    256
#define FEAT_DIM 20000
#define NBATCH   16
#define NBLK     640          // 8 Mtiles * 5 groups * 16 batches
#define BN_BLKS  160

typedef _Float16 half8 __attribute__((ext_vector_type(8)));
typedef float    f32x4 __attribute__((ext_vector_type(4)));

__device__ __forceinline__ void gbar(unsigned* cnt, unsigned target) {
    __syncthreads();
    if (threadIdx.x == 0) {
        __threadfence();
        __hip_atomic_fetch_add(cnt, 1u, __ATOMIC_ACQ_REL, __HIP_MEMORY_SCOPE_AGENT);
        while (__hip_atomic_load(cnt, __ATOMIC_ACQUIRE, __HIP_MEMORY_SCOPE_AGENT) < target) {
            __builtin_amdgcn_s_sleep(2);
        }
        __threadfence();
    }
    __syncthreads();
}

// ---------------------------------------------------------------------------
// Mega-kernel: conv-features (MFMA, fp16 3-term split) -> grid barrier ->
// fused BN+GEMV partials -> grid barrier -> final reduce. One launch.
// ---------------------------------------------------------------------------
__launch_bounds__(256, 4)
__global__ void mega(const float* __restrict__ x_enc,  // (16,256,3)
                     const float* __restrict__ Wk,     // (10000,3,9)
                     const float* __restrict__ bias,   // (10000,)
                     const float* __restrict__ gamma,
                     const float* __restrict__ beta,
                     const float* __restrict__ linW,   // (20000,10)
                     const float* __restrict__ linB,   // (10,)
                     float* __restrict__ feat,         // ws: (16,20000)
                     float* __restrict__ partial,      // ws: (160,160)
                     unsigned* __restrict__ bar,       // ws: 2 counters (pre-zeroed)
                     float* __restrict__ out)          // (16,10)
{
    __shared__ __align__(16) char smem[32768];
    _Float16* Bh = (_Float16*)smem;              // [4*256][8]  16 KB
    _Float16* Bl = (_Float16*)(smem + 16384);    // [4*256][8]  16 KB

    const int bid = blockIdx.x;
    const int tid = threadIdx.x;

    // ================= Phase 1: conv features =================
    {
        const int r8  = bid % 80;
        const int mt  = bid / 80;          // 0..7 (256 rows each)
        const int gi  = r8 >> 4;           // dilation group 0..4
        const int b   = r8 & 15;
        const int d   = 1 << gi;
        const int l   = tid & 63;
        const int wv  = tid >> 6;          // wave -> 64-row slice
        const int kb  = l >> 4;            // k-block 0..3
        const int lr  = l & 15;

        // ---- A fragments (weights + bias folded at k=27) -> registers ----
        half8 ahi[4], alo[4];
#pragma unroll
        for (int tt = 0; tt < 4; ++tt) {
            const int nl = mt * 256 + wv * 64 + tt * 16 + lr;
            const int n  = gi * GROUP + (nl < GROUP ? nl : GROUP - 1);
#pragma unroll
            for (int j = 0; j < 8; ++j) {
                const int k = kb * 8 + j;
                float w;
                if (k < 27)       w = Wk[n * 27 + k];
                else if (k == 27) w = bias[n];
                else              w = 0.f;
                const _Float16 h = (_Float16)w;
                ahi[tt][j] = h;
                alo[tt][j] = (_Float16)(w - (float)h);
            }
        }

        // ---- build B hi/lo in LDS from global x (no xp staging) ----
        // thread tid owns column t = tid; per q the k-block is q (compile-time)
#pragma unroll
        for (int q = 0; q < 4; ++q) {
            half8 hv, lv;
#pragma unroll
            for (int kk = 0; kk < 8; ++kk) {
                const int k2 = q * 8 + kk;
                float v = 0.f;
                if (k2 < 27) {
                    const int c  = k2 / 9;
                    const int k9 = k2 - c * 9;
                    const int t2 = tid + (k9 - 4) * d;
                    if (t2 >= 0 && t2 < SEQ_L)
                        v = x_enc[(b * SEQ_L + t2) * 3 + c];
                } else if (k2 == 27) {
                    v = 1.0f;              // bias row
                }
                const _Float16 h = (_Float16)v;
                hv[kk] = h;
                lv[kk] = (_Float16)(v - (float)h);
            }
            *(half8*)&Bh[(q * 256 + tid) * 8] = hv;
            *(half8*)&Bl[(q * 256 + tid) * 8] = lv;
        }
        __syncthreads();

        // ---- MFMA main loop: 16 N-chunks of 16 cols ----
        float mx[4][4];
        int   cnt[4][4];
#pragma unroll
        for (int tt = 0; tt < 4; ++tt)
#pragma unroll
            for (int r = 0; r < 4; ++r) { mx[tt][r] = -INFINITY; cnt[tt][r] = 0; }

#pragma unroll
        for (int ch = 0; ch < 16; ++ch) {
            const int t = ch * 16 + lr;
            const half8 bh = *(const half8*)&Bh[(kb * 256 + t) * 8];
            const half8 bl = *(const half8*)&Bl[(kb * 256 + t) * 8];
#pragma unroll
            for (int tt = 0; tt < 4; ++tt) {
                f32x4 acc = {0.f, 0.f, 0.f, 0.f};
                acc = __builtin_amdgcn_mfma_f32_16x16x32_f16(ahi[tt], bh, acc, 0, 0, 0);
                acc = __builtin_amdgcn_mfma_f32_16x16x32_f16(alo[tt], bh, acc, 0, 0, 0);
                acc = __builtin_amdgcn_mfma_f32_16x16x32_f16(ahi[tt], bl, acc, 0, 0, 0);
#pragma unroll
                for (int r = 0; r < 4; ++r) {
                    const float y = acc[r];
                    mx[tt][r]   = fmaxf(mx[tt][r], y);
                    cnt[tt][r] += (y > 0.f) ? 1 : 0;
                }
            }
        }

        // ---- reduce over 16 columns ----
#pragma unroll
        for (int tt = 0; tt < 4; ++tt)
#pragma unroll
            for (int r = 0; r < 4; ++r) {
#pragma unroll
                for (int m = 1; m < 16; m <<= 1) {
                    mx[tt][r]   = fmaxf(mx[tt][r], __shfl_xor(mx[tt][r], m));
                    cnt[tt][r] += __shfl_xor(cnt[tt][r], m);
                }
            }

        if (lr == 0) {
            float* fb = feat + b * FEAT_DIM + gi * 4000;
#pragma unroll
            for (int tt = 0; tt < 4; ++tt)
#pragma unroll
                for (int r = 0; r < 4; ++r) {
                    const int nl = mt * 256 + wv * 64 + tt * 16 + kb * 4 + r;
                    if (nl < GROUP) {
                        fb[nl]        = mx[tt][r];
                        fb[2000 + nl] = (float)cnt[tt][r] * (1.0f / 256.0f);
                    }
                }
        }
    }

    gbar(&bar[0], NBLK);

    // ================= Phase 2: BN + GEMV partials (blocks 0..159) =========
    if (bid < BN_BLKS) {
        float* gs = (float*)smem;          // 125
        float* hs = gs + 125;              // 125
        float* lw = hs + 125;              // 1250
        const int f0 = bid * 125;

        for (int i = tid; i < 1250; i += 256) lw[i] = linW[f0 * 10 + i];

        if (tid < 125) {
            const int f = f0 + tid;
            float s = 0.f, ss = 0.f;
#pragma unroll
            for (int b = 0; b < NBATCH; ++b) {
                const float v = feat[b * FEAT_DIM + f];
                s += v; ss += v * v;
            }
            const float mu  = s * (1.f / NBATCH);
            const float var = ss * (1.f / NBATCH) - mu * mu;
            const float gg  = gamma[f] * rsqrtf(var + 1e-5f);
            gs[tid] = gg;
            hs[tid] = beta[f] - mu * gg;
        }
        __syncthreads();

        const int bb = tid >> 4;           // batch 0..15
        const int ft = tid & 15;
        float acc[10];
#pragma unroll
        for (int c = 0; c < 10; ++c) acc[c] = 0.f;

        for (int i = ft; i < 125; i += 16) {
            const float tv = fmaf(feat[bb * FEAT_DIM + f0 + i], gs[i], hs[i]);
#pragma unroll
            for (int c = 0; c < 10; ++c) acc[c] = fmaf(tv, lw[i * 10 + c], acc[c]);
        }
#pragma unroll
        for (int c = 0; c < 10; ++c)
#pragma unroll
            for (int m = 1; m < 16; m <<= 1) acc[c] += __shfl_xor(acc[c], m);

        if (ft == 0) {
#pragma unroll
            for (int c = 0; c < 10; ++c)
                partial[(bid * NBATCH + bb) * 10 + c] = acc[c];
        }
    }

    gbar(&bar[1], NBLK);

    // ================= Phase 3: final reduce (block 0) =====================
    if (bid == 0 && tid < 160) {
        float s = linB[tid % 10];
        for (int sl = 0; sl < BN_BLKS; ++sl) s += partial[sl * 160 + tid];
        out[tid] = s;
    }
}

// ---------------------------------------------------------------------------
extern "C" void kernel_launch(void* const* d_in, const int* in_sizes, int n_in,
                              void* d_out, int out_size, void* d_ws, size_t ws_size,
                              hipStream_t stream) {
    const float* x     = (const float*)d_in[0];
    const float* Wk    = (const float*)d_in[1];
    const float* bias  = (const float*)d_in[2];
    const float* gamma = (const float*)d_in[3];
    const float* beta  = (const float*)d_in[4];
    const float* linW  = (const float*)d_in[5];
    const float* linB  = (const float*)d_in[6];
    float* out = (float*)d_out;

    float*    feat    = (float*)d_ws;                    // 320000 f
    float*    partial = feat + NBATCH * FEAT_DIM;        // 25600 f
    unsigned* bar     = (unsigned*)(partial + BN_BLKS * 160);  // 2 u32

    hipMemsetAsync(bar, 0, 2 * sizeof(unsigned), stream);
    mega<<<dim3(NBLK), 256, 0, stream>>>(x, Wk, bias, gamma, beta, linW, linB,
                                         feat, partial, bar, out);
}

// Round 10
// 100.862 us; speedup vs baseline: 2.2413x; 2.2413x over previous
//
#include <hip/hip_runtime.h>
#include <cmath>

#define NK       10000
#define GROUP    2000
#define SEQ_L    256
#define NBATCH   16
#define MROWS    64            // kernel rows per block
#define NPBLK    160           // 32 Mblocks * 5 groups

typedef _Float16 half8 __attribute__((ext_vector_type(8)));
typedef float    f32x4 __attribute__((ext_vector_type(4)));

// ---------------------------------------------------------------------------
// Kernel 1: fully fused conv(MFMA) + max/PPV + BN + GEMV-partial.
//   Block (blk_m, gi) owns 64 kernel rows x ALL 16 batches. Per batch:
//   build B (im2col hi/lo fp16, bias row at k=27) in LDS, 8 waves x 32 cols
//   MFMA, fold max/count, cross-wave combine into an LDS feature panel.
//   After the batch loop: BN stats + 10-class GEMV partial, all in-block.
// grid = (32, 5), block = 512.
// ---------------------------------------------------------------------------
__launch_bounds__(512)
__global__ void rocket_fused(const float* __restrict__ x_enc,  // (16,256,3)
                             const float* __restrict__ Wk,     // (10000,3,9)
                             const float* __restrict__ bias,   // (10000,)
                             const float* __restrict__ gamma,
                             const float* __restrict__ beta,
                             const float* __restrict__ linW,   // (20000,10)
                             float* __restrict__ partial)      // (160,16,10)
{
    __shared__ __align__(16) _Float16 Bh[1024 * 8];   // [q*256+t][j] 16 KB
    __shared__ __align__(16) _Float16 Bl[1024 * 8];   // 16 KB
    __shared__ float2 red[8][64];                     // per-wave partials 4 KB
    __shared__ float2 fsm[64][16];                    // feature panel 8 KB
    __shared__ float2 gh[128];                        // BN affine 1 KB

    const int blk_m = blockIdx.x;          // 0..31
    const int gi    = blockIdx.y;          // 0..4
    const int d     = 1 << gi;
    const int tid   = threadIdx.x;
    const int l     = tid & 63;
    const int wv    = tid >> 6;            // wave 0..7 -> 32-col slice
    const int kb    = l >> 4;              // k-block 0..3
    const int lr    = l & 15;

    // ---- A fragments (weights + bias folded at k=27) -> registers ----
    half8 ahi[4], alo[4];
#pragma unroll
    for (int tt = 0; tt < 4; ++tt) {
        const int nl = blk_m * MROWS + tt * 16 + lr;
        const int n  = gi * GROUP + (nl < GROUP ? nl : GROUP - 1);
#pragma unroll
        for (int j = 0; j < 8; ++j) {
            const int k = kb * 8 + j;
            float w;
            if (k < 27)       w = Wk[n * 27 + k];
            else if (k == 27) w = bias[n];
            else              w = 0.f;
            const _Float16 h = (_Float16)w;
            ahi[tt][j] = h;
            alo[tt][j] = (_Float16)(w - (float)h);
        }
    }

    // ================= batch loop =================
    for (int b = 0; b < NBATCH; ++b) {
        // ---- build B hi/lo in LDS (2 threads per column) ----
        {
            const int t  = tid & 255;
            const int qh = tid >> 8;           // 0..1
#pragma unroll
            for (int qq = 0; qq < 2; ++qq) {
                const int q = qh * 2 + qq;
                half8 hv, lv;
#pragma unroll
                for (int kk = 0; kk < 8; ++kk) {
                    const int k2 = q * 8 + kk;
                    float v = 0.f;
                    if (k2 < 27) {
                        const int c  = k2 / 9;
                        const int k9 = k2 - c * 9;
                        const int t2 = t + (k9 - 4) * d;
                        if (t2 >= 0 && t2 < SEQ_L)
                            v = x_enc[(b * SEQ_L + t2) * 3 + c];
                    } else if (k2 == 27) {
                        v = 1.0f;              // bias row
                    }
                    const _Float16 h = (_Float16)v;
                    hv[kk] = h;
                    lv[kk] = (_Float16)(v - (float)h);
                }
                *(half8*)&Bh[(q * 256 + t) * 8] = hv;
                *(half8*)&Bl[(q * 256 + t) * 8] = lv;
            }
        }
        __syncthreads();

        // ---- MFMA: this wave's 32 cols (2 chunks of 16) ----
        float mx[4][4];
        int   cnt[4][4];
#pragma unroll
        for (int tt = 0; tt < 4; ++tt)
#pragma unroll
            for (int r = 0; r < 4; ++r) { mx[tt][r] = -INFINITY; cnt[tt][r] = 0; }

#pragma unroll
        for (int ch = 0; ch < 2; ++ch) {
            const int t = wv * 32 + ch * 16 + lr;
            const half8 bh = *(const half8*)&Bh[(kb * 256 + t) * 8];
            const half8 bl = *(const half8*)&Bl[(kb * 256 + t) * 8];
#pragma unroll
            for (int tt = 0; tt < 4; ++tt) {
                f32x4 acc = {0.f, 0.f, 0.f, 0.f};
                acc = __builtin_amdgcn_mfma_f32_16x16x32_f16(ahi[tt], bh, acc, 0, 0, 0);
                acc = __builtin_amdgcn_mfma_f32_16x16x32_f16(alo[tt], bh, acc, 0, 0, 0);
                acc = __builtin_amdgcn_mfma_f32_16x16x32_f16(ahi[tt], bl, acc, 0, 0, 0);
#pragma unroll
                for (int r = 0; r < 4; ++r) {
                    const float y = acc[r];
                    mx[tt][r]   = fmaxf(mx[tt][r], y);
                    cnt[tt][r] += (y > 0.f) ? 1 : 0;
                }
            }
        }

        // ---- reduce over the 16 cols of each chunk-lane group ----
#pragma unroll
        for (int tt = 0; tt < 4; ++tt)
#pragma unroll
            for (int r = 0; r < 4; ++r) {
#pragma unroll
                for (int m = 1; m < 16; m <<= 1) {
                    mx[tt][r]   = fmaxf(mx[tt][r], __shfl_xor(mx[tt][r], m));
                    cnt[tt][r] += __shfl_xor(cnt[tt][r], m);
                }
            }
        if (lr == 0) {
#pragma unroll
            for (int tt = 0; tt < 4; ++tt)
#pragma unroll
                for (int r = 0; r < 4; ++r)
                    red[wv][tt * 16 + kb * 4 + r] =
                        make_float2(mx[tt][r], (float)cnt[tt][r]);
        }
        __syncthreads();

        // ---- combine 8 waves -> feature panel ----
        if (tid < MROWS) {
            float fm = -INFINITY, fc = 0.f;
#pragma unroll
            for (int w = 0; w < 8; ++w) {
                fm  = fmaxf(fm, red[w][tid].x);
                fc += red[w][tid].y;
            }
            fsm[tid][b] = make_float2(fm, fc * (1.0f / 256.0f));
        }
        __syncthreads();   // panel written; B safe to overwrite next batch
    }

    // ================= BN stats (128 features of this block) =================
    if (tid < 128) {
        const int  rloc  = tid & 63;
        const bool isppv = tid >= 64;
        float s = 0.f, ss = 0.f;
#pragma unroll
        for (int b = 0; b < NBATCH; ++b) {
            const float v = isppv ? fsm[rloc][b].y : fsm[rloc][b].x;
            s += v; ss += v * v;
        }
        const float mu  = s * (1.f / NBATCH);
        const float var = ss * (1.f / NBATCH) - mu * mu;
        const int   nl  = blk_m * MROWS + rloc;
        float gg = 0.f, hh = 0.f;
        if (nl < GROUP) {
            const int fg = gi * 4000 + (isppv ? 2000 : 0) + nl;
            gg = gamma[fg] * rsqrtf(var + 1e-5f);
            hh = beta[fg] - mu * gg;
        }
        gh[tid] = make_float2(gg, hh);
    }
    __syncthreads();

    // ================= GEMV partial (10 classes) =================
    {
        const int bb = tid >> 5;           // batch 0..15
        const int ft = tid & 31;
        float acc[10];
#pragma unroll
        for (int c = 0; c < 10; ++c) acc[c] = 0.f;

#pragma unroll
        for (int fi = 0; fi < 4; ++fi) {
            const int  f     = fi * 32 + ft;      // 0..127
            const int  rloc  = f & 63;
            const bool isppv = f >= 64;
            const float  v  = isppv ? fsm[rloc][bb].y : fsm[rloc][bb].x;
            const float2 G  = gh[f];
            const float  tv = fmaf(v, G.x, G.y);  // 0 for invalid rows
            const int nl = blk_m * MROWS + rloc;
            const int fg = gi * 4000 + (isppv ? 2000 : 0)
                         + (nl < GROUP ? nl : GROUP - 1);
#pragma unroll
            for (int c = 0; c < 10; ++c)
                acc[c] = fmaf(tv, linW[fg * 10 + c], acc[c]);
        }
#pragma unroll
        for (int c = 0; c < 10; ++c)
#pragma unroll
            for (int m = 1; m < 32; m <<= 1) acc[c] += __shfl_xor(acc[c], m);

        if (ft == 0) {
#pragma unroll
            for (int c = 0; c < 10; ++c)
                partial[((gi * 32 + blk_m) * NBATCH + bb) * 10 + c] = acc[c];
        }
    }
}

// ---------------------------------------------------------------------------
// Kernel 2: final reduce over 160 partial blocks + bias. 1 block, 640 thr.
// ---------------------------------------------------------------------------
__launch_bounds__(640)
__global__ void gemv_final(const float* __restrict__ partial,  // (160,160)
                           const float* __restrict__ linB,
                           float* __restrict__ out)            // (16,10)
{
    __shared__ float red2[4][160];
    const int tid = threadIdx.x;
    const int q   = tid / 160;      // 0..3
    const int o   = tid - q * 160;  // b*10 + c
    float s = 0.f;
    for (int sl = q; sl < NPBLK; sl += 4) s += partial[sl * 160 + o];
    red2[q][o] = s;
    __syncthreads();
    if (tid < 160)
        out[tid] = red2[0][tid] + red2[1][tid] + red2[2][tid] + red2[3][tid]
                 + linB[tid % 10];
}

// ---------------------------------------------------------------------------
extern "C" void kernel_launch(void* const* d_in, const int* in_sizes, int n_in,
                              void* d_out, int out_size, void* d_ws, size_t ws_size,
                              hipStream_t stream) {
    const float* x     = (const float*)d_in[0];
    const float* Wk    = (const float*)d_in[1];
    const float* bias  = (const float*)d_in[2];
    const float* gamma = (const float*)d_in[3];
    const float* beta  = (const float*)d_in[4];
    const float* linW  = (const float*)d_in[5];
    const float* linB  = (const float*)d_in[6];
    float* out = (float*)d_out;

    float* partial = (float*)d_ws;     // 160*160 floats

    rocket_fused<<<dim3(32, 5), 512, 0, stream>>>(x, Wk, bias, gamma, beta,
                                                  linW, partial);
    gemv_final<<<dim3(1), 640, 0, stream>>>(partial, linB, out);
}

// Round 11
// 44.890 us; speedup vs baseline: 5.0360x; 2.2469x over previous
//
#include <hip/hip_runtime.h>
#include <cmath>

#define NK       10000
#define GROUP    2000
#define SEQ_L    256
#define FEAT_DIM 20000
#define NBATCH   16

typedef _Float16 half8 __attribute__((ext_vector_type(8)));
typedef float    f32x4 __attribute__((ext_vector_type(4)));

// ---------------------------------------------------------------------------
// Kernel 1: build im2col B (hi/lo fp16 split) ONCE per (group, batch).
//   B[k'][t]: k' = c*9+k9 for k'<27, k'=27 is the bias row (=1), 28..31 zero.
//   Stored as [kb][t][j] (kb=k'>>3, j=k'&7): a GEMM fragment = 16 contig bytes.
// grid = (5, 16), block = 256.
// ---------------------------------------------------------------------------
__launch_bounds__(256)
__global__ void build_B(const float* __restrict__ x_enc,   // (16,256,3)
                        _Float16* __restrict__ Bh_g,
                        _Float16* __restrict__ Bl_g)
{
    __shared__ __align__(16) float xp[3 * 384];   // [c][t+64], zero-padded
    const int gi  = blockIdx.x;
    const int b   = blockIdx.y;
    const int d   = 1 << gi;
    const int tid = threadIdx.x;

    for (int i = tid; i < 3 * 384; i += 256) xp[i] = 0.f;
    __syncthreads();
    for (int e = tid; e < SEQ_L * 3; e += 256) {
        const int t = e / 3;
        const int c = e - t * 3;
        xp[c * 384 + 64 + t] = x_enc[(b * SEQ_L + t) * 3 + c];
    }
    __syncthreads();

    const int base = (gi * NBATCH + b) * 1024;    // 4 kb * 256 t
#pragma unroll
    for (int q = 0; q < 4; ++q) {
        const int idx = q * 256 + tid;            // kb*256 + t
        const int kb  = idx >> 8;
        const int t   = idx & 255;
        half8 hv, lv;
#pragma unroll
        for (int kk = 0; kk < 8; ++kk) {
            const int k2 = kb * 8 + kk;
            float v = 0.f;
            if (k2 < 27) {
                const int c  = (k2 >= 18) ? 2 : (k2 >= 9 ? 1 : 0);
                const int k9 = k2 - c * 9;
                v = xp[c * 384 + 64 + t + (k9 - 4) * d];
            } else if (k2 == 27) {
                v = 1.0f;                          // bias row
            }
            const _Float16 h = (_Float16)v;
            hv[kk] = h;
            lv[kk] = (_Float16)(v - (float)h);
        }
        *(half8*)&Bh_g[(base + idx) * 8] = hv;
        *(half8*)&Bl_g[(base + idx) * 8] = lv;
    }
}

// ---------------------------------------------------------------------------
// Kernel 2: MFMA GEMM + max/PPV epilogue. No LDS, no syncthreads. 128 thr =
//   2 waves x 64 rows (4 tiles of 16). B fragments = coalesced 16B global
//   loads (L2-hot). fp16 3-term split via TWO independent accumulator chains:
//   acc1 = Ahi*Bh (+ Alo*Bh chained), acc2 = Ahi*Bl; y = acc1 + acc2.
// grid = (16 Mtiles, 5 groups, 16 batches).
// ---------------------------------------------------------------------------
__launch_bounds__(128)
__global__ void gemm_feat(const _Float16* __restrict__ Bh_g,
                          const _Float16* __restrict__ Bl_g,
                          const float* __restrict__ Wk,     // (10000,3,9)
                          const float* __restrict__ bias,   // (10000,)
                          float* __restrict__ feat)         // (16,20000)
{
    const int mt  = blockIdx.x;
    const int gi  = blockIdx.y;
    const int b   = blockIdx.z;
    const int tid = threadIdx.x;
    const int l   = tid & 63;
    const int wv  = tid >> 6;
    const int kb  = l >> 4;            // k-block 0..3
    const int lr  = l & 15;

    // A fragments: lane holds row = mt*128 + wv*64 + tt*16 + lr, k = kb*8+j
    // (bias folded in at k = 27)
    half8 ahi[4], alo[4];
#pragma unroll
    for (int tt = 0; tt < 4; ++tt) {
        const int nl = mt * 128 + wv * 64 + tt * 16 + lr;
        const int n  = gi * GROUP + (nl < GROUP ? nl : GROUP - 1);
#pragma unroll
        for (int j = 0; j < 8; ++j) {
            const int k = kb * 8 + j;
            float w;
            if (k < 27)       w = Wk[n * 27 + k];
            else if (k == 27) w = bias[n];
            else              w = 0.f;
            const _Float16 h = (_Float16)w;
            ahi[tt][j] = h;
            alo[tt][j] = (_Float16)(w - (float)h);
        }
    }

    const _Float16* bhp = Bh_g + ((gi * NBATCH + b) * 1024 + kb * 256) * 8;
    const _Float16* blp = Bl_g + ((gi * NBATCH + b) * 1024 + kb * 256) * 8;

    float mx[4][4];
    int   cnt[4][4];
#pragma unroll
    for (int tt = 0; tt < 4; ++tt)
#pragma unroll
        for (int r = 0; r < 4; ++r) { mx[tt][r] = -INFINITY; cnt[tt][r] = 0; }

#pragma unroll
    for (int ch = 0; ch < 16; ++ch) {
        const int t = ch * 16 + lr;
        const half8 bh = *(const half8*)&bhp[t * 8];
        const half8 bl = *(const half8*)&blp[t * 8];
#pragma unroll
        for (int tt = 0; tt < 4; ++tt) {
            f32x4 acc1 = {0.f, 0.f, 0.f, 0.f};
            f32x4 acc2 = {0.f, 0.f, 0.f, 0.f};
            acc1 = __builtin_amdgcn_mfma_f32_16x16x32_f16(ahi[tt], bh, acc1, 0, 0, 0);
            acc2 = __builtin_amdgcn_mfma_f32_16x16x32_f16(ahi[tt], bl, acc2, 0, 0, 0);
            acc1 = __builtin_amdgcn_mfma_f32_16x16x32_f16(alo[tt], bh, acc1, 0, 0, 0);
#pragma unroll
            for (int r = 0; r < 4; ++r) {
                const float y = acc1[r] + acc2[r];   // bias already included
                mx[tt][r]   = fmaxf(mx[tt][r], y);
                cnt[tt][r] += (y > 0.f) ? 1 : 0;
            }
        }
    }

    // reduce over the 16 columns (lanes with same row group)
#pragma unroll
    for (int tt = 0; tt < 4; ++tt)
#pragma unroll
        for (int r = 0; r < 4; ++r) {
#pragma unroll
            for (int m = 1; m < 16; m <<= 1) {
                mx[tt][r]   = fmaxf(mx[tt][r], __shfl_xor(mx[tt][r], m));
                cnt[tt][r] += __shfl_xor(cnt[tt][r], m);
            }
        }

    if (lr == 0) {
        float* fb = feat + b * FEAT_DIM + gi * 4000;
#pragma unroll
        for (int tt = 0; tt < 4; ++tt)
#pragma unroll
            for (int r = 0; r < 4; ++r) {
                const int nl = mt * 128 + wv * 64 + tt * 16 + kb * 4 + r;
                if (nl < GROUP) {
                    fb[nl]        = mx[tt][r];
                    fb[2000 + nl] = (float)cnt[tt][r] * (1.0f / 256.0f);
                }
            }
    }
}

// ---------------------------------------------------------------------------
// Kernel 3: fused BN-stats + GEMV partial. 160 slices of 125 features;
//   linW slice staged coalesced in LDS.
// ---------------------------------------------------------------------------
__launch_bounds__(256)
__global__ void bn_gemv(const float* __restrict__ feat,
                        const float* __restrict__ gamma,
                        const float* __restrict__ beta,
                        const float* __restrict__ linW,   // (20000,10)
                        float* __restrict__ partial)      // (160,16,10)
{
    __shared__ float gs[125], hs[125];
    __shared__ float lw[125 * 10];
    const int sl  = blockIdx.x;
    const int f0  = sl * 125;
    const int tid = threadIdx.x;

    for (int i = tid; i < 1250; i += 256) lw[i] = linW[f0 * 10 + i];

    if (tid < 125) {
        const int f = f0 + tid;
        float s = 0.f, ss = 0.f;
#pragma unroll
        for (int b = 0; b < NBATCH; ++b) {
            const float v = feat[b * FEAT_DIM + f];
            s += v; ss += v * v;
        }
        const float mu  = s * (1.f / NBATCH);
        const float var = ss * (1.f / NBATCH) - mu * mu;
        const float gg  = gamma[f] * rsqrtf(var + 1e-5f);
        gs[tid] = gg;
        hs[tid] = beta[f] - mu * gg;
    }
    __syncthreads();

    const int bb = tid >> 4;        // batch 0..15
    const int ft = tid & 15;
    float acc[10];
#pragma unroll
    for (int c = 0; c < 10; ++c) acc[c] = 0.f;

    for (int i = ft; i < 125; i += 16) {
        const float tv = fmaf(feat[bb * FEAT_DIM + f0 + i], gs[i], hs[i]);
#pragma unroll
        for (int c = 0; c < 10; ++c) acc[c] = fmaf(tv, lw[i * 10 + c], acc[c]);
    }
#pragma unroll
    for (int c = 0; c < 10; ++c)
#pragma unroll
        for (int m = 1; m < 16; m <<= 1) acc[c] += __shfl_xor(acc[c], m);

    if (ft == 0) {
#pragma unroll
        for (int c = 0; c < 10; ++c)
            partial[(sl * NBATCH + bb) * 10 + c] = acc[c];
    }
}

// ---------------------------------------------------------------------------
// Kernel 4: final reduce over 160 slices + bias. 1 block, 640 threads.
// ---------------------------------------------------------------------------
__launch_bounds__(640)
__global__ void gemv_final(const float* __restrict__ partial,  // (160,160)
                           const float* __restrict__ linB,
                           float* __restrict__ out)            // (16,10)
{
    __shared__ float red[4][160];
    const int tid = threadIdx.x;
    const int q   = tid / 160;      // 0..3
    const int o   = tid - q * 160;  // b*10 + c
    float s = 0.f;
    for (int sl = q; sl < 160; sl += 4) s += partial[sl * 160 + o];
    red[q][o] = s;
    __syncthreads();
    if (tid < 160)
        out[tid] = red[0][tid] + red[1][tid] + red[2][tid] + red[3][tid]
                 + linB[tid % 10];
}

// ---------------------------------------------------------------------------
extern "C" void kernel_launch(void* const* d_in, const int* in_sizes, int n_in,
                              void* d_out, int out_size, void* d_ws, size_t ws_size,
                              hipStream_t stream) {
    const float* x     = (const float*)d_in[0];
    const float* Wk    = (const float*)d_in[1];
    const float* bias  = (const float*)d_in[2];
    const float* gamma = (const float*)d_in[3];
    const float* beta  = (const float*)d_in[4];
    const float* linW  = (const float*)d_in[5];
    const float* linB  = (const float*)d_in[6];
    float* out = (float*)d_out;

    float*    feat    = (float*)d_ws;                       // 320000 f
    float*    partial = feat + NBATCH * FEAT_DIM;           // 25600 f
    _Float16* Bh      = (_Float16*)(partial + 160 * 160);   // 655360 h
    _Float16* Bl      = Bh + 5 * NBATCH * 1024 * 8;         // 655360 h

    build_B<<<dim3(5, NBATCH), 256, 0, stream>>>(x, Bh, Bl);
    gemm_feat<<<dim3(16, 5, NBATCH), 128, 0, stream>>>(Bh, Bl, Wk, bias, feat);
    bn_gemv<<<dim3(160), 256, 0, stream>>>(feat, gamma, beta, linW, partial);
    gemv_final<<<dim3(1), 640, 0, stream>>>(partial, linB, out);
}

// Round 12
// 42.854 us; speedup vs baseline: 5.2753x; 1.0475x over previous
//
#include <hip/hip_runtime.h>
#include <cmath>

#define NK       10000
#define GROUP    2000
#define SEQ_L    256
#define FEAT_DIM 20000
#define NBATCH   16
#define NSLICE   160

typedef _Float16 half8 __attribute__((ext_vector_type(8)));
typedef float    f32x4 __attribute__((ext_vector_type(4)));

// ---------------------------------------------------------------------------
// Kernel 1: fused im2col-build + MFMA GEMM + max/PPV (R9 phase-1, validated).
//   Block (mt, gi, b): 256 kernel rows x 256 positions. B (hi/lo fp16 split,
//   bias row at k=27) built direct from global x into LDS (one sync).
//   3-term split (Ahi*Bh + Alo*Bh + Ahi*Bl) = ~f32 accuracy.
// grid = (8, 5, 16), block = 256 (4 waves x 64 rows).
// ---------------------------------------------------------------------------
__launch_bounds__(256)
__global__ void conv_feat(const float* __restrict__ x_enc,  // (16,256,3)
                          const float* __restrict__ Wk,     // (10000,3,9)
                          const float* __restrict__ bias,   // (10000,)
                          float* __restrict__ feat)         // (16,20000)
{
    __shared__ __align__(16) _Float16 Bh[1024 * 8];   // [q*256+t][j] 16 KB
    __shared__ __align__(16) _Float16 Bl[1024 * 8];   // 16 KB

    const int mt  = blockIdx.x;        // 0..7 (256 rows each)
    const int gi  = blockIdx.y;        // dilation group 0..4
    const int b   = blockIdx.z;
    const int d   = 1 << gi;
    const int tid = threadIdx.x;
    const int l   = tid & 63;
    const int wv  = tid >> 6;          // wave -> 64-row slice
    const int kb  = l >> 4;            // k-block 0..3
    const int lr  = l & 15;

    // ---- A fragments (weights + bias folded at k=27) -> registers ----
    half8 ahi[4], alo[4];
#pragma unroll
    for (int tt = 0; tt < 4; ++tt) {
        const int nl = mt * 256 + wv * 64 + tt * 16 + lr;
        const int n  = gi * GROUP + (nl < GROUP ? nl : GROUP - 1);
#pragma unroll
        for (int j = 0; j < 8; ++j) {
            const int k = kb * 8 + j;
            float w;
            if (k < 27)       w = Wk[n * 27 + k];
            else if (k == 27) w = bias[n];
            else              w = 0.f;
            const _Float16 h = (_Float16)w;
            ahi[tt][j] = h;
            alo[tt][j] = (_Float16)(w - (float)h);
        }
    }

    // ---- build B hi/lo in LDS direct from global x (thread = column t) ----
#pragma unroll
    for (int q = 0; q < 4; ++q) {
        half8 hv, lv;
#pragma unroll
        for (int kk = 0; kk < 8; ++kk) {
            const int k2 = q * 8 + kk;
            float v = 0.f;
            if (k2 < 27) {
                const int c  = k2 / 9;
                const int k9 = k2 - c * 9;
                const int t2 = tid + (k9 - 4) * d;
                if (t2 >= 0 && t2 < SEQ_L)
                    v = x_enc[(b * SEQ_L + t2) * 3 + c];
            } else if (k2 == 27) {
                v = 1.0f;              // bias row
            }
            const _Float16 h = (_Float16)v;
            hv[kk] = h;
            lv[kk] = (_Float16)(v - (float)h);
        }
        *(half8*)&Bh[(q * 256 + tid) * 8] = hv;
        *(half8*)&Bl[(q * 256 + tid) * 8] = lv;
    }
    __syncthreads();

    // ---- MFMA main loop: 16 N-chunks of 16 cols ----
    float mx[4][4];
    int   cnt[4][4];
#pragma unroll
    for (int tt = 0; tt < 4; ++tt)
#pragma unroll
        for (int r = 0; r < 4; ++r) { mx[tt][r] = -INFINITY; cnt[tt][r] = 0; }

#pragma unroll
    for (int ch = 0; ch < 16; ++ch) {
        const int t = ch * 16 + lr;
        const half8 bh = *(const half8*)&Bh[(kb * 256 + t) * 8];
        const half8 bl = *(const half8*)&Bl[(kb * 256 + t) * 8];
#pragma unroll
        for (int tt = 0; tt < 4; ++tt) {
            f32x4 acc = {0.f, 0.f, 0.f, 0.f};
            acc = __builtin_amdgcn_mfma_f32_16x16x32_f16(ahi[tt], bh, acc, 0, 0, 0);
            acc = __builtin_amdgcn_mfma_f32_16x16x32_f16(alo[tt], bh, acc, 0, 0, 0);
            acc = __builtin_amdgcn_mfma_f32_16x16x32_f16(ahi[tt], bl, acc, 0, 0, 0);
#pragma unroll
            for (int r = 0; r < 4; ++r) {
                const float y = acc[r];            // bias already included
                mx[tt][r]   = fmaxf(mx[tt][r], y);
                cnt[tt][r] += (y > 0.f) ? 1 : 0;
            }
        }
    }

    // ---- reduce over 16 columns ----
#pragma unroll
    for (int tt = 0; tt < 4; ++tt)
#pragma unroll
        for (int r = 0; r < 4; ++r) {
#pragma unroll
            for (int m = 1; m < 16; m <<= 1) {
                mx[tt][r]   = fmaxf(mx[tt][r], __shfl_xor(mx[tt][r], m));
                cnt[tt][r] += __shfl_xor(cnt[tt][r], m);
            }
        }

    if (lr == 0) {
        float* fb = feat + b * FEAT_DIM + gi * 4000;
#pragma unroll
        for (int tt = 0; tt < 4; ++tt)
#pragma unroll
            for (int r = 0; r < 4; ++r) {
                const int nl = mt * 256 + wv * 64 + tt * 16 + kb * 4 + r;
                if (nl < GROUP) {
                    fb[nl]        = mx[tt][r];
                    fb[2000 + nl] = (float)cnt[tt][r] * (1.0f / 256.0f);
                }
            }
    }
}

// ---------------------------------------------------------------------------
// Kernel 2: fused BN-stats + GEMV partial + last-block final reduce.
//   160 blocks x 256 thr; block sl handles 125 features. After writing its
//   partials: syncthreads (drains stores), thread0 threadfence (L2 wb) +
//   device-scope atomicAdd; the 160th arriver reduces all partials in FIXED
//   order (deterministic) using agent-scope atomic loads (stale-L2 safe).
// ---------------------------------------------------------------------------
__launch_bounds__(256)
__global__ void bn_gemv_final(const float* __restrict__ feat,
                              const float* __restrict__ gamma,
                              const float* __restrict__ beta,
                              const float* __restrict__ linW,   // (20000,10)
                              const float* __restrict__ linB,   // (10,)
                              float* __restrict__ partial,      // (160,16,10)
                              unsigned* __restrict__ counter,   // pre-zeroed
                              float* __restrict__ out)          // (16,10)
{
    __shared__ float gs[125], hs[125];
    __shared__ float lw[125 * 10];
    __shared__ int   lastflag;
    const int sl  = blockIdx.x;
    const int f0  = sl * 125;
    const int tid = threadIdx.x;

    for (int i = tid; i < 1250; i += 256) lw[i] = linW[f0 * 10 + i];

    if (tid < 125) {
        const int f = f0 + tid;
        float s = 0.f, ss = 0.f;
#pragma unroll
        for (int b = 0; b < NBATCH; ++b) {
            const float v = feat[b * FEAT_DIM + f];
            s += v; ss += v * v;
        }
        const float mu  = s * (1.f / NBATCH);
        const float var = ss * (1.f / NBATCH) - mu * mu;
        const float gg  = gamma[f] * rsqrtf(var + 1e-5f);
        gs[tid] = gg;
        hs[tid] = beta[f] - mu * gg;
    }
    __syncthreads();

    const int bb = tid >> 4;        // batch 0..15
    const int ft = tid & 15;
    float acc[10];
#pragma unroll
    for (int c = 0; c < 10; ++c) acc[c] = 0.f;

    for (int i = ft; i < 125; i += 16) {
        const float tv = fmaf(feat[bb * FEAT_DIM + f0 + i], gs[i], hs[i]);
#pragma unroll
        for (int c = 0; c < 10; ++c) acc[c] = fmaf(tv, lw[i * 10 + c], acc[c]);
    }
#pragma unroll
    for (int c = 0; c < 10; ++c)
#pragma unroll
        for (int m = 1; m < 16; m <<= 1) acc[c] += __shfl_xor(acc[c], m);

    if (ft == 0) {
#pragma unroll
        for (int c = 0; c < 10; ++c)
            partial[(sl * NBATCH + bb) * 10 + c] = acc[c];
    }

    // ---- arrival protocol (no spinning): last block reduces ----
    __syncthreads();                 // drains this block's partial stores
    if (tid == 0) {
        __threadfence();             // device-scope: writeback local L2
        const unsigned old =
            __hip_atomic_fetch_add(counter, 1u, __ATOMIC_ACQ_REL,
                                   __HIP_MEMORY_SCOPE_AGENT);
        lastflag = (old == NSLICE - 1);
    }
    __syncthreads();

    if (lastflag) {
        __threadfence();
        if (tid < 160) {             // o = b*10 + c
            float s = linB[tid % 10];
            for (int q = 0; q < NSLICE; ++q)
                s += __hip_atomic_load(&partial[q * 160 + tid],
                                       __ATOMIC_RELAXED,
                                       __HIP_MEMORY_SCOPE_AGENT);
            out[tid] = s;
        }
    }
}

// ---------------------------------------------------------------------------
extern "C" void kernel_launch(void* const* d_in, const int* in_sizes, int n_in,
                              void* d_out, int out_size, void* d_ws, size_t ws_size,
                              hipStream_t stream) {
    const float* x     = (const float*)d_in[0];
    const float* Wk    = (const float*)d_in[1];
    const float* bias  = (const float*)d_in[2];
    const float* gamma = (const float*)d_in[3];
    const float* beta  = (const float*)d_in[4];
    const float* linW  = (const float*)d_in[5];
    const float* linB  = (const float*)d_in[6];
    float* out = (float*)d_out;

    float*    feat    = (float*)d_ws;                    // 320000 f
    float*    partial = feat + NBATCH * FEAT_DIM;        // 25600 f
    unsigned* counter = (unsigned*)(partial + NSLICE * 160);

    hipMemsetAsync(counter, 0, sizeof(unsigned), stream);
    conv_feat<<<dim3(8, 5, NBATCH), 256, 0, stream>>>(x, Wk, bias, feat);
    bn_gemv_final<<<dim3(NSLICE), 256, 0, stream>>>(feat, gamma, beta, linW,
                                                    linB, partial, counter, out);
}

// Round 13
// 38.603 us; speedup vs baseline: 5.8562x; 1.1101x over previous
//
#include <hip/hip_runtime.h>
#include <cmath>

#define NK       10000
#define GROUP    2000
#define SEQ_L    256
#define FEAT_DIM 20000
#define NBATCH   16
#define NSLICE   40
#define SLICE_F  500

typedef _Float16 half8 __attribute__((ext_vector_type(8)));
typedef float    f32x4 __attribute__((ext_vector_type(4)));

// ---------------------------------------------------------------------------
// Kernel 1: build im2col B (hi/lo fp16 split) once per (group, batch).
//   B[k'][t]: k' = c*9+k9 for k'<27; k'=27 = bias row (1.0); 28..31 zero.
//   Layout [kb][t][j] (kb=k'>>3, j=k'&7): GEMM fragment = 16 contig bytes.
//   Thread (0,0,0) also zeroes the arrival counter for kernel 3.
// grid = (5, 16), block = 256.
// ---------------------------------------------------------------------------
__launch_bounds__(256)
__global__ void build_B(const float* __restrict__ x_enc,   // (16,256,3)
                        _Float16* __restrict__ Bh_g,
                        _Float16* __restrict__ Bl_g,
                        unsigned* __restrict__ counter)
{
    __shared__ __align__(16) float xp[3 * 384];   // [c][t+64], zero-padded
    const int gi  = blockIdx.x;
    const int b   = blockIdx.y;
    const int d   = 1 << gi;
    const int tid = threadIdx.x;

    if (gi == 0 && b == 0 && tid == 0)
        __hip_atomic_store(counter, 0u, __ATOMIC_RELEASE, __HIP_MEMORY_SCOPE_AGENT);

    for (int i = tid; i < 3 * 384; i += 256) xp[i] = 0.f;
    __syncthreads();
    for (int e = tid; e < SEQ_L * 3; e += 256) {
        const int t = e / 3;
        const int c = e - t * 3;
        xp[c * 384 + 64 + t] = x_enc[(b * SEQ_L + t) * 3 + c];
    }
    __syncthreads();

    const int base = (gi * NBATCH + b) * 1024;    // 4 kb * 256 t
#pragma unroll
    for (int q = 0; q < 4; ++q) {
        const int idx = q * 256 + tid;            // kb*256 + t
        const int kb  = idx >> 8;
        const int t   = idx & 255;
        half8 hv, lv;
#pragma unroll
        for (int kk = 0; kk < 8; ++kk) {
            const int k2 = kb * 8 + kk;
            float v = 0.f;
            if (k2 < 27) {
                const int c  = (k2 >= 18) ? 2 : (k2 >= 9 ? 1 : 0);
                const int k9 = k2 - c * 9;
                v = xp[c * 384 + 64 + t + (k9 - 4) * d];
            } else if (k2 == 27) {
                v = 1.0f;                          // bias row
            }
            const _Float16 h = (_Float16)v;
            hv[kk] = h;
            lv[kk] = (_Float16)(v - (float)h);
        }
        *(half8*)&Bh_g[(base + idx) * 8] = hv;
        *(half8*)&Bl_g[(base + idx) * 8] = lv;
    }
}

// ---------------------------------------------------------------------------
// Kernel 2: MFMA GEMM + max/PPV epilogue. No LDS, no syncthreads. 128 thr =
//   2 waves x 64 rows (4 tiles of 16). B fragments = coalesced 16B global
//   loads (L2-hot). 3-term fp16 split (Ahi*Bh + Alo*Bh + Ahi*Bl), bias
//   folded in at k=27 -> epilogue is pure max/count.
// grid = (16 Mtiles, 5 groups, 16 batches).
// ---------------------------------------------------------------------------
__launch_bounds__(128)
__global__ void gemm_feat(const _Float16* __restrict__ Bh_g,
                          const _Float16* __restrict__ Bl_g,
                          const float* __restrict__ Wk,     // (10000,3,9)
                          const float* __restrict__ bias,   // (10000,)
                          float* __restrict__ feat)         // (16,20000)
{
    const int mt  = blockIdx.x;
    const int gi  = blockIdx.y;
    const int b   = blockIdx.z;
    const int tid = threadIdx.x;
    const int l   = tid & 63;
    const int wv  = tid >> 6;
    const int kb  = l >> 4;            // k-block 0..3
    const int lr  = l & 15;

    // A fragments: lane holds row = mt*128 + wv*64 + tt*16 + lr, k = kb*8+j
    half8 ahi[4], alo[4];
#pragma unroll
    for (int tt = 0; tt < 4; ++tt) {
        const int nl = mt * 128 + wv * 64 + tt * 16 + lr;
        const int n  = gi * GROUP + (nl < GROUP ? nl : GROUP - 1);
#pragma unroll
        for (int j = 0; j < 8; ++j) {
            const int k = kb * 8 + j;
            float w;
            if (k < 27)       w = Wk[n * 27 + k];
            else if (k == 27) w = bias[n];
            else              w = 0.f;
            const _Float16 h = (_Float16)w;
            ahi[tt][j] = h;
            alo[tt][j] = (_Float16)(w - (float)h);
        }
    }

    const _Float16* bhp = Bh_g + ((gi * NBATCH + b) * 1024 + kb * 256) * 8;
    const _Float16* blp = Bl_g + ((gi * NBATCH + b) * 1024 + kb * 256) * 8;

    float mx[4][4];
    int   cnt[4][4];
#pragma unroll
    for (int tt = 0; tt < 4; ++tt)
#pragma unroll
        for (int r = 0; r < 4; ++r) { mx[tt][r] = -INFINITY; cnt[tt][r] = 0; }

#pragma unroll
    for (int ch = 0; ch < 16; ++ch) {
        const int t = ch * 16 + lr;
        const half8 bh = *(const half8*)&bhp[t * 8];
        const half8 bl = *(const half8*)&blp[t * 8];
#pragma unroll
        for (int tt = 0; tt < 4; ++tt) {
            f32x4 acc = {0.f, 0.f, 0.f, 0.f};
            acc = __builtin_amdgcn_mfma_f32_16x16x32_f16(ahi[tt], bh, acc, 0, 0, 0);
            acc = __builtin_amdgcn_mfma_f32_16x16x32_f16(alo[tt], bh, acc, 0, 0, 0);
            acc = __builtin_amdgcn_mfma_f32_16x16x32_f16(ahi[tt], bl, acc, 0, 0, 0);
#pragma unroll
            for (int r = 0; r < 4; ++r) {
                const float y = acc[r];            // bias already included
                mx[tt][r]   = fmaxf(mx[tt][r], y);
                cnt[tt][r] += (y > 0.f) ? 1 : 0;
            }
        }
    }

    // reduce over the 16 columns (lanes with same row group)
#pragma unroll
    for (int tt = 0; tt < 4; ++tt)
#pragma unroll
        for (int r = 0; r < 4; ++r) {
#pragma unroll
            for (int m = 1; m < 16; m <<= 1) {
                mx[tt][r]   = fmaxf(mx[tt][r], __shfl_xor(mx[tt][r], m));
                cnt[tt][r] += __shfl_xor(cnt[tt][r], m);
            }
        }

    if (lr == 0) {
        float* fb = feat + b * FEAT_DIM + gi * 4000;
#pragma unroll
        for (int tt = 0; tt < 4; ++tt)
#pragma unroll
            for (int r = 0; r < 4; ++r) {
                const int nl = mt * 128 + wv * 64 + tt * 16 + kb * 4 + r;
                if (nl < GROUP) {
                    fb[nl]        = mx[tt][r];
                    fb[2000 + nl] = (float)cnt[tt][r] * (1.0f / 256.0f);
                }
            }
    }
}

// ---------------------------------------------------------------------------
// Kernel 3: fused BN-stats + GEMV partial + last-arriver final reduce.
//   40 blocks x 256 thr; block sl owns 500 features. Arrival protocol
//   validated in R12: syncthreads -> thread0 threadfence + device atomicAdd;
//   the 40th arriver reduces all partials in FIXED order (deterministic)
//   via agent-scope loads.
// ---------------------------------------------------------------------------
__launch_bounds__(256)
__global__ void bn_gemv_final(const float* __restrict__ feat,
                              const float* __restrict__ gamma,
                              const float* __restrict__ beta,
                              const float* __restrict__ linW,   // (20000,10)
                              const float* __restrict__ linB,   // (10,)
                              float* __restrict__ partial,      // (40,16,10)
                              unsigned* __restrict__ counter,   // zeroed by build_B
                              float* __restrict__ out)          // (16,10)
{
    __shared__ float gs[SLICE_F], hs[SLICE_F];
    __shared__ float lw[SLICE_F * 10];
    __shared__ int   lastflag;
    const int sl  = blockIdx.x;
    const int f0  = sl * SLICE_F;
    const int tid = threadIdx.x;

    for (int i = tid; i < SLICE_F * 10; i += 256) lw[i] = linW[f0 * 10 + i];

    for (int i = tid; i < SLICE_F; i += 256) {
        const int f = f0 + i;
        float s = 0.f, ss = 0.f;
#pragma unroll
        for (int b = 0; b < NBATCH; ++b) {
            const float v = feat[b * FEAT_DIM + f];
            s += v; ss += v * v;
        }
        const float mu  = s * (1.f / NBATCH);
        const float var = ss * (1.f / NBATCH) - mu * mu;
        const float gg  = gamma[f] * rsqrtf(var + 1e-5f);
        gs[i] = gg;
        hs[i] = beta[f] - mu * gg;
    }
    __syncthreads();

    const int bb = tid >> 4;        // batch 0..15
    const int ft = tid & 15;
    float acc[10];
#pragma unroll
    for (int c = 0; c < 10; ++c) acc[c] = 0.f;

    for (int i = ft; i < SLICE_F; i += 16) {
        const float tv = fmaf(feat[bb * FEAT_DIM + f0 + i], gs[i], hs[i]);
#pragma unroll
        for (int c = 0; c < 10; ++c) acc[c] = fmaf(tv, lw[i * 10 + c], acc[c]);
    }
#pragma unroll
    for (int c = 0; c < 10; ++c)
#pragma unroll
        for (int m = 1; m < 16; m <<= 1) acc[c] += __shfl_xor(acc[c], m);

    if (ft == 0) {
#pragma unroll
        for (int c = 0; c < 10; ++c)
            partial[(sl * NBATCH + bb) * 10 + c] = acc[c];
    }

    // ---- arrival protocol (no spinning): last block reduces ----
    __syncthreads();                 // drains this block's partial stores
    if (tid == 0) {
        __threadfence();             // device-scope writeback
        const unsigned old =
            __hip_atomic_fetch_add(counter, 1u, __ATOMIC_ACQ_REL,
                                   __HIP_MEMORY_SCOPE_AGENT);
        lastflag = (old == NSLICE - 1);
    }
    __syncthreads();

    if (lastflag) {
        __threadfence();
        if (tid < 160) {             // o = b*10 + c
            float s = linB[tid % 10];
#pragma unroll
            for (int q = 0; q < NSLICE; ++q)
                s += __hip_atomic_load(&partial[q * 160 + tid],
                                       __ATOMIC_RELAXED,
                                       __HIP_MEMORY_SCOPE_AGENT);
            out[tid] = s;
        }
    }
}

// ---------------------------------------------------------------------------
extern "C" void kernel_launch(void* const* d_in, const int* in_sizes, int n_in,
                              void* d_out, int out_size, void* d_ws, size_t ws_size,
                              hipStream_t stream) {
    const float* x     = (const float*)d_in[0];
    const float* Wk    = (const float*)d_in[1];
    const float* bias  = (const float*)d_in[2];
    const float* gamma = (const float*)d_in[3];
    const float* beta  = (const float*)d_in[4];
    const float* linW  = (const float*)d_in[5];
    const float* linB  = (const float*)d_in[6];
    float* out = (float*)d_out;

    float*    feat    = (float*)d_ws;                    // 320000 f
    float*    partial = feat + NBATCH * FEAT_DIM;        // 6400 f
    unsigned* counter = (unsigned*)(partial + NSLICE * 160);
    _Float16* Bh      = (_Float16*)(counter + 4);        // 655360 h
    _Float16* Bl      = Bh + 5 * NBATCH * 1024 * 8;      // 655360 h

    build_B<<<dim3(5, NBATCH), 256, 0, stream>>>(x, Bh, Bl, counter);
    gemm_feat<<<dim3(16, 5, NBATCH), 128, 0, stream>>>(Bh, Bl, Wk, bias, feat);
    bn_gemv_final<<<dim3(NSLICE), 256, 0, stream>>>(feat, gamma, beta, linW,
                                                    linB, partial, counter, out);
}